// Round 5
// baseline (65.062 us; speedup 1.0000x reference)
//
#include <hip/hip_runtime.h>

// CrossConvV2: B=2, n=1024, d=3, f=3, m=26 probes, k=5 convs, o=6 out_feats.
// out[b,l] = [coords(3) | leakyrelu( (wf flat 78 * 10/n) @ W[k] + b[k] ) (30)]
// wf[b,l,m,ff] = sum_nn 1/(|c_nn - c_l - p_m|^2 + 10) * feats[nn,ff]
// |c_nn - c_l - p|^2 + 10 = |d|^2 + 19 - 2 d.p   (|p| = 3 for all probes)
//
// R4: occupancy push. Measured busy% vs resident waves: 2048w->26%,
// 4096w->44%, 12288w->66% (latency-bound, not issue-bound). Split the
// nn-sum in half as well: wave = (center, probe-half, nn-half) ->
// 8192 waves = 32/CU = 100% occupancy. VGPR<=64 enforced (R2 measured 52).

#define NPTS      1024
#define COEFF     10.0f
#define NEG       0.3f

constexpr float PROBE[26][3] = {
  {-2.12132034f,  1.95984445f, -0.81179415f},
  {-2.12132034f,  1.95984445f,  0.81179415f},
  {-2.12132034f,  0.81179415f,  1.95984445f},
  {-2.12132034f, -0.81179415f,  1.95984445f},
  {-2.12132034f, -1.95984445f,  0.81179415f},
  {-2.12132034f, -1.95984445f, -0.81179415f},
  {-2.12132034f, -0.81179415f, -1.95984445f},
  {-2.12132034f,  0.81179415f, -1.95984445f},
  { 0.0f,         3.0f,         0.0f       },
  { 0.0f,         2.12132034f,  2.12132034f},
  { 0.0f,         0.0f,         3.0f       },
  { 0.0f,        -2.12132034f,  2.12132034f},
  { 0.0f,        -3.0f,         0.0f       },
  { 0.0f,        -2.12132034f, -2.12132034f},
  { 0.0f,         0.0f,        -3.0f       },
  { 0.0f,         2.12132034f, -2.12132034f},
  { 2.12132034f,  1.95984445f,  0.81179415f},
  { 2.12132034f,  0.81179415f,  1.95984445f},
  { 2.12132034f, -0.81179415f,  1.95984445f},
  { 2.12132034f, -1.95984445f,  0.81179415f},
  { 2.12132034f, -1.95984445f, -0.81179415f},
  { 2.12132034f, -0.81179415f, -1.95984445f},
  { 2.12132034f,  0.81179415f, -1.95984445f},
  { 2.12132034f,  1.95984445f, -0.81179415f},
  {-3.0f,         0.0f,         0.0f       },
  { 3.0f,         0.0f,         0.0f       },
};

// half0: ring x=-2.121 (8) + y/z-axials (4) + x-axials (2) = 14 probes
// half1: ring x=+2.121 (8) + diagonal quads (4)            = 12 probes
constexpr int H0[14] = {0,1,2,3,4,5,6,7, 8,12,10,14, 24,25};
constexpr int H1[14] = {16,17,18,19,20,21,22,23, 9,11,13,15, 0,0}; // pad

// wave64 sum-reduce via DPP (result valid in lane 63). rocPRIM pattern.
#define DPP_STEP(x, ctrl, rm, bm, bc)                                        \
  x += __int_as_float(__builtin_amdgcn_update_dpp(                           \
      0, __float_as_int(x), ctrl, rm, bm, bc))

__device__ __forceinline__ float wave_sum_to_lane63(float x) {
  DPP_STEP(x, 0x111, 0xf, 0xf, true);   // row_shr:1
  DPP_STEP(x, 0x112, 0xf, 0xf, true);   // row_shr:2
  DPP_STEP(x, 0x114, 0xf, 0xe, false);  // row_shr:4
  DPP_STEP(x, 0x118, 0xf, 0xc, false);  // row_shr:8
  DPP_STEP(x, 0x142, 0xa, 0xf, false);  // row_bcast:15 -> rows 1,3
  DPP_STEP(x, 0x143, 0xc, 0xf, false);  // row_bcast:31 -> rows 2,3
  return x;                              // lane 63 = full sum
}

// t-generation with compile-time zero-skip; shared subtrees CSE via GVN
template <int HALF, int J>
struct TGen {
  static __device__ __forceinline__ void run(float base, float dx, float dy,
                                             float dz, float* t) {
    TGen<HALF, J - 1>::run(base, dx, dy, dz, t);
    constexpr int   m   = HALF ? H1[J] : H0[J];
    constexpr float px2 = -2.0f * PROBE[m][0];
    constexpr float py2 = -2.0f * PROBE[m][1];
    constexpr float pz2 = -2.0f * PROBE[m][2];
    float v = base;                         // x innermost: ring-shared CSE
    if constexpr (px2 != 0.0f) v = fmaf(px2, dx, v);
    if constexpr (py2 != 0.0f) v = fmaf(py2, dy, v);
    if constexpr (pz2 != 0.0f) v = fmaf(pz2, dz, v);
    t[J] = v;
  }
};
template <int HALF>
struct TGen<HALF, -1> {
  static __device__ __forceinline__ void run(float, float, float, float, float*) {}
};

// batched reciprocal: 1 rcp + 9 mul for 4 values (vs 4 rcp)
__device__ __forceinline__ void rcp4(const float* t, float* w) {
  const float p01 = t[0] * t[1], p23 = t[2] * t[3];
  const float r   = __builtin_amdgcn_rcpf(p01 * p23);
  const float r01 = p23 * r, r23 = p01 * r;
  w[0] = t[1] * r01;  w[1] = t[0] * r01;
  w[2] = t[3] * r23;  w[3] = t[2] * r23;
}
__device__ __forceinline__ void rcp2(const float* t, float* w) {
  const float r = __builtin_amdgcn_rcpf(t[0] * t[1]);
  w[0] = t[1] * r;  w[1] = t[0] * r;
}

template <int HALF>
__device__ __forceinline__ void run_main(const float* __restrict__ batch,
                                         int row0, int lane, float cx, float cy,
                                         float cz, float* acc) {
  constexpr int NP = HALF ? 12 : 14;
  for (int it = 0; it < NPTS / 128; ++it) {      // 8 iters (nn-half)
    const float* prow = batch + (row0 + it * 64 + lane) * 6;
    const float2 q0 = *reinterpret_cast<const float2*>(prow);
    const float2 q1 = *reinterpret_cast<const float2*>(prow + 2);
    const float2 q2 = *reinterpret_cast<const float2*>(prow + 4);
    const float dx = q0.x - cx, dy = q0.y - cy, dz = q1.x - cz;
    const float f0 = q1.y, f1 = q2.x, f2 = q2.y;
    const float base = fmaf(dx, dx, fmaf(dy, dy, fmaf(dz, dz, 19.0f)));

    float t[NP], w[NP];
    TGen<HALF, NP - 1>::run(base, dx, dy, dz, t);
    rcp4(t + 0, w + 0);
    rcp4(t + 4, w + 4);
    rcp4(t + 8, w + 8);
    if constexpr (NP == 14) rcp2(t + 12, w + 12);

    #pragma unroll
    for (int j = 0; j < NP; ++j) {
      acc[j * 3 + 0] = fmaf(w[j], f0, acc[j * 3 + 0]);
      acc[j * 3 + 1] = fmaf(w[j], f1, acc[j * 3 + 1]);
      acc[j * 3 + 2] = fmaf(w[j], f2, acc[j * 3 + 2]);
    }
  }
}

template <int HALF>
__device__ __forceinline__ void reduce_store(float* acc, int lane, float* sxSlot,
                                             float scale) {
  constexpr int NP = HALF ? 12 : 14;
  #pragma unroll
  for (int j = 0; j < NP * 3; ++j)
    acc[j] = wave_sum_to_lane63(acc[j]) * scale;
  if (lane == 63) {
    #pragma unroll
    for (int j = 0; j < NP; ++j) {
      const int m = HALF ? H1[j] : H0[j];
      sxSlot[m * 3 + 0] = acc[j * 3 + 0];
      sxSlot[m * 3 + 1] = acc[j * 3 + 1];
      sxSlot[m * 3 + 2] = acc[j * 3 + 2];
    }
  }
}

__global__ __launch_bounds__(512, 8) void crossconv_kernel(
    const float* __restrict__ points,  // (2,1024,6)
    const float* __restrict__ W,       // (5,78,6)
    const float* __restrict__ bias,    // (5,6) flat 30
    float* __restrict__ out)           // (2,1024,33)
{
    // sx[center][nnHalf][value]
    __shared__ __align__(16) float sx[2][2][80];

    const int tid    = threadIdx.x;
    const int lane   = tid & 63;
    const int wv     = tid >> 6;          // wave in block: 0..7
    const int cLocal = wv >> 2;           // center within block: 0,1
    const int half   = (wv >> 1) & 1;     // probe half: 0,1
    const int nnH    = wv & 1;            // neighbor half: 0,1
    const int G      = blockIdx.x * 2 + cLocal;   // global center 0..2047

    const float* batch = points + (G >> 10) * (NPTS * 6);
    const float* crow  = points + G * 6;
    const float  cx = crow[0], cy = crow[1], cz = crow[2];
    const int    row0 = nnH * (NPTS / 2);

    float acc[42];
    #pragma unroll
    for (int j = 0; j < 42; ++j) acc[j] = 0.f;

    if (half == 0) run_main<0>(batch, row0, lane, cx, cy, cz, acc);
    else           run_main<1>(batch, row0, lane, cx, cy, cz, acc);

    const float scale = COEFF / (float)NPTS;
    if (half == 0) reduce_store<0>(acc, lane, sx[cLocal][nnH], scale);
    else           reduce_store<1>(acc, lane, sx[cLocal][nnH], scale);
    __syncthreads();

    // tail: waves 0,4 (half==0 && nnH==0) do the 78->30 matmul + coords
    if (half == 0 && nnH == 0) {
      float* orow = out + G * 33;
      if (lane < 30) {
        const int k = lane / 6, o = lane % 6;
        const float* Wk = W + k * (78 * 6) + o;  // W[k, t, o], stride 6 over t
        float h0 = bias[lane], h1 = 0.f, h2 = 0.f, h3 = 0.f;
        const float4* s0 = reinterpret_cast<const float4*>(sx[cLocal][0]);
        const float4* s1 = reinterpret_cast<const float4*>(sx[cLocal][1]);
        #pragma unroll
        for (int t4 = 0; t4 < 19; ++t4) {
          const float4 a = s0[t4], b = s1[t4];
          h0 = fmaf(a.x + b.x, Wk[(t4 * 4 + 0) * 6], h0);
          h1 = fmaf(a.y + b.y, Wk[(t4 * 4 + 1) * 6], h1);
          h2 = fmaf(a.z + b.z, Wk[(t4 * 4 + 2) * 6], h2);
          h3 = fmaf(a.w + b.w, Wk[(t4 * 4 + 3) * 6], h3);
        }
        h0 = fmaf(sx[cLocal][0][76] + sx[cLocal][1][76], Wk[76 * 6], h0);
        h1 = fmaf(sx[cLocal][0][77] + sx[cLocal][1][77], Wk[77 * 6], h1);
        float h = (h0 + h2) + (h1 + h3);
        h = (h > 0.f) ? h : NEG * h;
        orow[3 + lane] = h;
      } else if (lane < 33) {
        orow[lane - 30] = (lane == 30) ? cx : ((lane == 31) ? cy : cz);
      }
    }
}

extern "C" void kernel_launch(void* const* d_in, const int* in_sizes, int n_in,
                              void* d_out, int out_size, void* d_ws, size_t ws_size,
                              hipStream_t stream) {
    const float* points = (const float*)d_in[0];  // 2*1024*6
    const float* W      = (const float*)d_in[1];  // 5*78*6
    const float* bias   = (const float*)d_in[2];  // 30
    float* out          = (float*)d_out;          // 2*1024*33
    // 1024 blocks x 8 waves = 2048 centers x 2 probe-halves x 2 nn-halves
    crossconv_kernel<<<1024, 512, 0, stream>>>(points, W, bias, out);
}

// Round 6
// 26.439 us; speedup vs baseline: 2.4609x; 2.4609x over previous
//
#include <hip/hip_runtime.h>

// CrossConvV2: B=2, n=1024, d=3, f=3, m=26 probes, k=5 convs, o=6 out_feats.
// out[b,l] = [coords(3) | leakyrelu( (wf flat 78 * 10/n) @ W[k] + b[k] ) (30)]
// wf[b,l,m,ff] = sum_nn 1/(|c_nn - c_l - p_m|^2 + 10) * feats[nn,ff]
// |c_nn - c_l - p|^2 + 10 = |d|^2 + 19 - 2 d.p   (|p| = 3 for all probes)
//
// R5: occupancy via grid, not launch_bounds. R4's launch_bounds(512,8)
// clamped VGPR to 32 -> 135MB scratch spill -> 65us. Fix: keep R3's exact
// inner loop (measured 52 VGPR, no spill) and launch_bounds(256,4) (cap 128),
// but block = 1 center x 4 waves (probe-half x nn-half), grid = 2048 blocks
// -> 8192 waves. HW fits 8 waves/SIMD from actual VGPR=52 (8x52=416<=512),
// regardless of the launch_bounds promise.

#define NPTS      1024
#define COEFF     10.0f
#define NEG       0.3f

constexpr float PROBE[26][3] = {
  {-2.12132034f,  1.95984445f, -0.81179415f},
  {-2.12132034f,  1.95984445f,  0.81179415f},
  {-2.12132034f,  0.81179415f,  1.95984445f},
  {-2.12132034f, -0.81179415f,  1.95984445f},
  {-2.12132034f, -1.95984445f,  0.81179415f},
  {-2.12132034f, -1.95984445f, -0.81179415f},
  {-2.12132034f, -0.81179415f, -1.95984445f},
  {-2.12132034f,  0.81179415f, -1.95984445f},
  { 0.0f,         3.0f,         0.0f       },
  { 0.0f,         2.12132034f,  2.12132034f},
  { 0.0f,         0.0f,         3.0f       },
  { 0.0f,        -2.12132034f,  2.12132034f},
  { 0.0f,        -3.0f,         0.0f       },
  { 0.0f,        -2.12132034f, -2.12132034f},
  { 0.0f,         0.0f,        -3.0f       },
  { 0.0f,         2.12132034f, -2.12132034f},
  { 2.12132034f,  1.95984445f,  0.81179415f},
  { 2.12132034f,  0.81179415f,  1.95984445f},
  { 2.12132034f, -0.81179415f,  1.95984445f},
  { 2.12132034f, -1.95984445f,  0.81179415f},
  { 2.12132034f, -1.95984445f, -0.81179415f},
  { 2.12132034f, -0.81179415f, -1.95984445f},
  { 2.12132034f,  0.81179415f, -1.95984445f},
  { 2.12132034f,  1.95984445f, -0.81179415f},
  {-3.0f,         0.0f,         0.0f       },
  { 3.0f,         0.0f,         0.0f       },
};

// half0: ring x=-2.121 (8) + y/z-axials (4) + x-axials (2) = 14 probes
// half1: ring x=+2.121 (8) + diagonal quads (4)            = 12 probes
constexpr int H0[14] = {0,1,2,3,4,5,6,7, 8,12,10,14, 24,25};
constexpr int H1[14] = {16,17,18,19,20,21,22,23, 9,11,13,15, 0,0}; // pad

// wave64 sum-reduce via DPP (result valid in lane 63). rocPRIM pattern.
#define DPP_STEP(x, ctrl, rm, bm, bc)                                        \
  x += __int_as_float(__builtin_amdgcn_update_dpp(                           \
      0, __float_as_int(x), ctrl, rm, bm, bc))

__device__ __forceinline__ float wave_sum_to_lane63(float x) {
  DPP_STEP(x, 0x111, 0xf, 0xf, true);   // row_shr:1
  DPP_STEP(x, 0x112, 0xf, 0xf, true);   // row_shr:2
  DPP_STEP(x, 0x114, 0xf, 0xe, false);  // row_shr:4
  DPP_STEP(x, 0x118, 0xf, 0xc, false);  // row_shr:8
  DPP_STEP(x, 0x142, 0xa, 0xf, false);  // row_bcast:15 -> rows 1,3
  DPP_STEP(x, 0x143, 0xc, 0xf, false);  // row_bcast:31 -> rows 2,3
  return x;                              // lane 63 = full sum
}

// t-generation with compile-time zero-skip; shared subtrees CSE via GVN
template <int HALF, int J>
struct TGen {
  static __device__ __forceinline__ void run(float base, float dx, float dy,
                                             float dz, float* t) {
    TGen<HALF, J - 1>::run(base, dx, dy, dz, t);
    constexpr int   m   = HALF ? H1[J] : H0[J];
    constexpr float px2 = -2.0f * PROBE[m][0];
    constexpr float py2 = -2.0f * PROBE[m][1];
    constexpr float pz2 = -2.0f * PROBE[m][2];
    float v = base;                         // x innermost: ring-shared CSE
    if constexpr (px2 != 0.0f) v = fmaf(px2, dx, v);
    if constexpr (py2 != 0.0f) v = fmaf(py2, dy, v);
    if constexpr (pz2 != 0.0f) v = fmaf(pz2, dz, v);
    t[J] = v;
  }
};
template <int HALF>
struct TGen<HALF, -1> {
  static __device__ __forceinline__ void run(float, float, float, float, float*) {}
};

// batched reciprocal: 1 rcp + 9 mul for 4 values (vs 4 rcp)
__device__ __forceinline__ void rcp4(const float* t, float* w) {
  const float p01 = t[0] * t[1], p23 = t[2] * t[3];
  const float r   = __builtin_amdgcn_rcpf(p01 * p23);
  const float r01 = p23 * r, r23 = p01 * r;
  w[0] = t[1] * r01;  w[1] = t[0] * r01;
  w[2] = t[3] * r23;  w[3] = t[2] * r23;
}
__device__ __forceinline__ void rcp2(const float* t, float* w) {
  const float r = __builtin_amdgcn_rcpf(t[0] * t[1]);
  w[0] = t[1] * r;  w[1] = t[0] * r;
}

template <int HALF>
__device__ __forceinline__ void run_main(const float* __restrict__ batch,
                                         int row0, int lane, float cx, float cy,
                                         float cz, float* acc) {
  constexpr int NP = HALF ? 12 : 14;
  for (int it = 0; it < NPTS / 128; ++it) {      // 8 iters (nn-half)
    const float* prow = batch + (row0 + it * 64 + lane) * 6;
    const float2 q0 = *reinterpret_cast<const float2*>(prow);
    const float2 q1 = *reinterpret_cast<const float2*>(prow + 2);
    const float2 q2 = *reinterpret_cast<const float2*>(prow + 4);
    const float dx = q0.x - cx, dy = q0.y - cy, dz = q1.x - cz;
    const float f0 = q1.y, f1 = q2.x, f2 = q2.y;
    const float base = fmaf(dx, dx, fmaf(dy, dy, fmaf(dz, dz, 19.0f)));

    float t[NP], w[NP];
    TGen<HALF, NP - 1>::run(base, dx, dy, dz, t);
    rcp4(t + 0, w + 0);
    rcp4(t + 4, w + 4);
    rcp4(t + 8, w + 8);
    if constexpr (NP == 14) rcp2(t + 12, w + 12);

    #pragma unroll
    for (int j = 0; j < NP; ++j) {
      acc[j * 3 + 0] = fmaf(w[j], f0, acc[j * 3 + 0]);
      acc[j * 3 + 1] = fmaf(w[j], f1, acc[j * 3 + 1]);
      acc[j * 3 + 2] = fmaf(w[j], f2, acc[j * 3 + 2]);
    }
  }
}

template <int HALF>
__device__ __forceinline__ void reduce_store(float* acc, int lane, float* sxSlot,
                                             float scale) {
  constexpr int NP = HALF ? 12 : 14;
  #pragma unroll
  for (int j = 0; j < NP * 3; ++j)
    acc[j] = wave_sum_to_lane63(acc[j]) * scale;
  if (lane == 63) {
    #pragma unroll
    for (int j = 0; j < NP; ++j) {
      const int m = HALF ? H1[j] : H0[j];
      sxSlot[m * 3 + 0] = acc[j * 3 + 0];
      sxSlot[m * 3 + 1] = acc[j * 3 + 1];
      sxSlot[m * 3 + 2] = acc[j * 3 + 2];
    }
  }
}

__global__ __launch_bounds__(256, 4) void crossconv_kernel(
    const float* __restrict__ points,  // (2,1024,6)
    const float* __restrict__ W,       // (5,78,6)
    const float* __restrict__ bias,    // (5,6) flat 30
    float* __restrict__ out)           // (2,1024,33)
{
    // sx[nnHalf][value] — block owns ONE center
    __shared__ __align__(16) float sx[2][80];

    const int tid  = threadIdx.x;
    const int lane = tid & 63;
    const int wv   = tid >> 6;            // wave in block: 0..3
    const int half = wv >> 1;             // probe half: 0,1
    const int nnH  = wv & 1;              // neighbor half: 0,1
    const int G    = blockIdx.x;          // global center 0..2047

    const float* batch = points + (G >> 10) * (NPTS * 6);
    const float* crow  = points + G * 6;
    const float  cx = crow[0], cy = crow[1], cz = crow[2];
    const int    row0 = nnH * (NPTS / 2);

    float acc[42];
    #pragma unroll
    for (int j = 0; j < 42; ++j) acc[j] = 0.f;

    if (half == 0) run_main<0>(batch, row0, lane, cx, cy, cz, acc);
    else           run_main<1>(batch, row0, lane, cx, cy, cz, acc);

    const float scale = COEFF / (float)NPTS;
    if (half == 0) reduce_store<0>(acc, lane, sx[nnH], scale);
    else           reduce_store<1>(acc, lane, sx[nnH], scale);
    __syncthreads();

    // tail: wave 0 (half==0, nnH==0) does the 78->30 matmul + coords
    if (wv == 0) {
      float* orow = out + G * 33;
      if (lane < 30) {
        const int k = lane / 6, o = lane % 6;
        const float* Wk = W + k * (78 * 6) + o;  // W[k, t, o], stride 6 over t
        float h0 = bias[lane], h1 = 0.f, h2 = 0.f, h3 = 0.f;
        const float4* s0 = reinterpret_cast<const float4*>(sx[0]);
        const float4* s1 = reinterpret_cast<const float4*>(sx[1]);
        #pragma unroll
        for (int t4 = 0; t4 < 19; ++t4) {
          const float4 a = s0[t4], b = s1[t4];
          h0 = fmaf(a.x + b.x, Wk[(t4 * 4 + 0) * 6], h0);
          h1 = fmaf(a.y + b.y, Wk[(t4 * 4 + 1) * 6], h1);
          h2 = fmaf(a.z + b.z, Wk[(t4 * 4 + 2) * 6], h2);
          h3 = fmaf(a.w + b.w, Wk[(t4 * 4 + 3) * 6], h3);
        }
        h0 = fmaf(sx[0][76] + sx[1][76], Wk[76 * 6], h0);
        h1 = fmaf(sx[0][77] + sx[1][77], Wk[77 * 6], h1);
        float h = (h0 + h2) + (h1 + h3);
        h = (h > 0.f) ? h : NEG * h;
        orow[3 + lane] = h;
      } else if (lane < 33) {
        orow[lane - 30] = (lane == 30) ? cx : ((lane == 31) ? cy : cz);
      }
    }
}

extern "C" void kernel_launch(void* const* d_in, const int* in_sizes, int n_in,
                              void* d_out, int out_size, void* d_ws, size_t ws_size,
                              hipStream_t stream) {
    const float* points = (const float*)d_in[0];  // 2*1024*6
    const float* W      = (const float*)d_in[1];  // 5*78*6
    const float* bias   = (const float*)d_in[2];  // 30
    float* out          = (float*)d_out;          // 2*1024*33
    // 2048 blocks (1 center each) x 4 waves = 8192 waves
    crossconv_kernel<<<2048, 256, 0, stream>>>(points, W, bias, out);
}

// Round 7
// 26.375 us; speedup vs baseline: 2.4668x; 1.0024x over previous
//
#include <hip/hip_runtime.h>

// CrossConvV2: B=2, n=1024, d=3, f=3, m=26 probes, k=5 convs, o=6 out_feats.
// out[b,l] = [coords(3) | leakyrelu( (wf flat 78 * 10/n) @ W[k] + b[k] ) (30)]
// wf[b,l,m,ff] = sum_nn 1/(|c_nn - c_l - p_m|^2 + 10) * feats[nn,ff]
// |c_nn - c_l - p|^2 + 10 = |d|^2 + 19 - 2 d.p   (|p| = 3 for all probes)
//
// R6: LDS-stage the 24KB points batch per block (coalesced float4 pass),
// inner loop reads rows from LDS (24B stride = 2-way bank alias = free).
// Theory: R1-R5 flat at ~24-26us regardless of waves/instructions because
// the 24B-strided global loads (24 cache lines per wave-load) saturate the
// per-CU TA/L1 path; VALUBusy pinned 30-66% at any occupancy. LDS removes
// that pipe from the inner loop. Block = 512 thr = 2 centers x half x nnH.

#define NPTS      1024
#define COEFF     10.0f
#define NEG       0.3f

constexpr float PROBE[26][3] = {
  {-2.12132034f,  1.95984445f, -0.81179415f},
  {-2.12132034f,  1.95984445f,  0.81179415f},
  {-2.12132034f,  0.81179415f,  1.95984445f},
  {-2.12132034f, -0.81179415f,  1.95984445f},
  {-2.12132034f, -1.95984445f,  0.81179415f},
  {-2.12132034f, -1.95984445f, -0.81179415f},
  {-2.12132034f, -0.81179415f, -1.95984445f},
  {-2.12132034f,  0.81179415f, -1.95984445f},
  { 0.0f,         3.0f,         0.0f       },
  { 0.0f,         2.12132034f,  2.12132034f},
  { 0.0f,         0.0f,         3.0f       },
  { 0.0f,        -2.12132034f,  2.12132034f},
  { 0.0f,        -3.0f,         0.0f       },
  { 0.0f,        -2.12132034f, -2.12132034f},
  { 0.0f,         0.0f,        -3.0f       },
  { 0.0f,         2.12132034f, -2.12132034f},
  { 2.12132034f,  1.95984445f,  0.81179415f},
  { 2.12132034f,  0.81179415f,  1.95984445f},
  { 2.12132034f, -0.81179415f,  1.95984445f},
  { 2.12132034f, -1.95984445f,  0.81179415f},
  { 2.12132034f, -1.95984445f, -0.81179415f},
  { 2.12132034f, -0.81179415f, -1.95984445f},
  { 2.12132034f,  0.81179415f, -1.95984445f},
  { 2.12132034f,  1.95984445f, -0.81179415f},
  {-3.0f,         0.0f,         0.0f       },
  { 3.0f,         0.0f,         0.0f       },
};

// half0: ring x=-2.121 (8) + y/z-axials (4) + x-axials (2) = 14 probes
// half1: ring x=+2.121 (8) + diagonal quads (4)            = 12 probes
constexpr int H0[14] = {0,1,2,3,4,5,6,7, 8,12,10,14, 24,25};
constexpr int H1[14] = {16,17,18,19,20,21,22,23, 9,11,13,15, 0,0}; // pad

// wave64 sum-reduce via DPP (result valid in lane 63). rocPRIM pattern.
#define DPP_STEP(x, ctrl, rm, bm, bc)                                        \
  x += __int_as_float(__builtin_amdgcn_update_dpp(                           \
      0, __float_as_int(x), ctrl, rm, bm, bc))

__device__ __forceinline__ float wave_sum_to_lane63(float x) {
  DPP_STEP(x, 0x111, 0xf, 0xf, true);   // row_shr:1
  DPP_STEP(x, 0x112, 0xf, 0xf, true);   // row_shr:2
  DPP_STEP(x, 0x114, 0xf, 0xe, false);  // row_shr:4
  DPP_STEP(x, 0x118, 0xf, 0xc, false);  // row_shr:8
  DPP_STEP(x, 0x142, 0xa, 0xf, false);  // row_bcast:15 -> rows 1,3
  DPP_STEP(x, 0x143, 0xc, 0xf, false);  // row_bcast:31 -> rows 2,3
  return x;                              // lane 63 = full sum
}

// t-generation with compile-time zero-skip; shared subtrees CSE via GVN
template <int HALF, int J>
struct TGen {
  static __device__ __forceinline__ void run(float base, float dx, float dy,
                                             float dz, float* t) {
    TGen<HALF, J - 1>::run(base, dx, dy, dz, t);
    constexpr int   m   = HALF ? H1[J] : H0[J];
    constexpr float px2 = -2.0f * PROBE[m][0];
    constexpr float py2 = -2.0f * PROBE[m][1];
    constexpr float pz2 = -2.0f * PROBE[m][2];
    float v = base;                         // x innermost: ring-shared CSE
    if constexpr (px2 != 0.0f) v = fmaf(px2, dx, v);
    if constexpr (py2 != 0.0f) v = fmaf(py2, dy, v);
    if constexpr (pz2 != 0.0f) v = fmaf(pz2, dz, v);
    t[J] = v;
  }
};
template <int HALF>
struct TGen<HALF, -1> {
  static __device__ __forceinline__ void run(float, float, float, float, float*) {}
};

// batched reciprocal: 1 rcp + 9 mul for 4 values (vs 4 rcp)
__device__ __forceinline__ void rcp4(const float* t, float* w) {
  const float p01 = t[0] * t[1], p23 = t[2] * t[3];
  const float r   = __builtin_amdgcn_rcpf(p01 * p23);
  const float r01 = p23 * r, r23 = p01 * r;
  w[0] = t[1] * r01;  w[1] = t[0] * r01;
  w[2] = t[3] * r23;  w[3] = t[2] * r23;
}
__device__ __forceinline__ void rcp2(const float* t, float* w) {
  const float r = __builtin_amdgcn_rcpf(t[0] * t[1]);
  w[0] = t[1] * r;  w[1] = t[0] * r;
}

template <int HALF>
__device__ __forceinline__ void run_main(const float* __restrict__ pts,
                                         int row0, int lane, float cx, float cy,
                                         float cz, float* acc) {
  constexpr int NP = HALF ? 12 : 14;
  for (int it = 0; it < NPTS / 128; ++it) {      // 8 iters (nn-half)
    const float* prow = pts + (row0 + it * 64 + lane) * 6;
    const float2 q0 = *reinterpret_cast<const float2*>(prow);      // ds_read_b64
    const float2 q1 = *reinterpret_cast<const float2*>(prow + 2);
    const float2 q2 = *reinterpret_cast<const float2*>(prow + 4);
    const float dx = q0.x - cx, dy = q0.y - cy, dz = q1.x - cz;
    const float f0 = q1.y, f1 = q2.x, f2 = q2.y;
    const float base = fmaf(dx, dx, fmaf(dy, dy, fmaf(dz, dz, 19.0f)));

    float t[NP], w[NP];
    TGen<HALF, NP - 1>::run(base, dx, dy, dz, t);
    rcp4(t + 0, w + 0);
    rcp4(t + 4, w + 4);
    rcp4(t + 8, w + 8);
    if constexpr (NP == 14) rcp2(t + 12, w + 12);

    #pragma unroll
    for (int j = 0; j < NP; ++j) {
      acc[j * 3 + 0] = fmaf(w[j], f0, acc[j * 3 + 0]);
      acc[j * 3 + 1] = fmaf(w[j], f1, acc[j * 3 + 1]);
      acc[j * 3 + 2] = fmaf(w[j], f2, acc[j * 3 + 2]);
    }
  }
}

template <int HALF>
__device__ __forceinline__ void reduce_store(float* acc, int lane, float* sxSlot,
                                             float scale) {
  constexpr int NP = HALF ? 12 : 14;
  #pragma unroll
  for (int j = 0; j < NP * 3; ++j)
    acc[j] = wave_sum_to_lane63(acc[j]) * scale;
  if (lane == 63) {
    #pragma unroll
    for (int j = 0; j < NP; ++j) {
      const int m = HALF ? H1[j] : H0[j];
      sxSlot[m * 3 + 0] = acc[j * 3 + 0];
      sxSlot[m * 3 + 1] = acc[j * 3 + 1];
      sxSlot[m * 3 + 2] = acc[j * 3 + 2];
    }
  }
}

__global__ __launch_bounds__(512, 4) void crossconv_kernel(
    const float* __restrict__ points,  // (2,1024,6)
    const float* __restrict__ W,       // (5,78,6)
    const float* __restrict__ bias,    // (5,6) flat 30
    float* __restrict__ out)           // (2,1024,33)
{
    __shared__ __align__(16) float pts[NPTS * 6];   // 24 KB: whole batch
    __shared__ __align__(16) float sx[2][2][80];    // [center][nnHalf][value]

    const int tid    = threadIdx.x;
    const int lane   = tid & 63;
    const int wv     = tid >> 6;          // wave in block: 0..7
    const int cLocal = wv >> 2;           // center within block: 0,1
    const int half   = (wv >> 1) & 1;     // probe half: 0,1
    const int nnH    = wv & 1;            // neighbor half: 0,1
    const int G      = blockIdx.x * 2 + cLocal;   // global center 0..2047

    // stage whole batch into LDS: 1536 float4s, 512 threads x 3, coalesced
    {
      const float4* src = reinterpret_cast<const float4*>(
          points + (blockIdx.x >> 9) * (NPTS * 6));
      float4* dst = reinterpret_cast<float4*>(pts);
      #pragma unroll
      for (int k = 0; k < 3; ++k)
        dst[tid + 512 * k] = src[tid + 512 * k];
    }
    __syncthreads();

    const int   ci = ((blockIdx.x & 511) << 1) | cLocal;  // center row in batch
    const float cx = pts[ci * 6 + 0], cy = pts[ci * 6 + 1], cz = pts[ci * 6 + 2];
    const int   row0 = nnH * (NPTS / 2);

    float acc[42];
    #pragma unroll
    for (int j = 0; j < 42; ++j) acc[j] = 0.f;

    if (half == 0) run_main<0>(pts, row0, lane, cx, cy, cz, acc);
    else           run_main<1>(pts, row0, lane, cx, cy, cz, acc);

    const float scale = COEFF / (float)NPTS;
    if (half == 0) reduce_store<0>(acc, lane, sx[cLocal][nnH], scale);
    else           reduce_store<1>(acc, lane, sx[cLocal][nnH], scale);
    __syncthreads();

    // tail: waves 0,4 (half==0 && nnH==0) do the 78->30 matmul + coords
    if (half == 0 && nnH == 0) {
      float* orow = out + G * 33;
      if (lane < 30) {
        const int k = lane / 6, o = lane % 6;
        const float* Wk = W + k * (78 * 6) + o;  // W[k, t, o], stride 6 over t
        float h0 = bias[lane], h1 = 0.f, h2 = 0.f, h3 = 0.f;
        const float4* s0 = reinterpret_cast<const float4*>(sx[cLocal][0]);
        const float4* s1 = reinterpret_cast<const float4*>(sx[cLocal][1]);
        #pragma unroll
        for (int t4 = 0; t4 < 19; ++t4) {
          const float4 a = s0[t4], b = s1[t4];
          h0 = fmaf(a.x + b.x, Wk[(t4 * 4 + 0) * 6], h0);
          h1 = fmaf(a.y + b.y, Wk[(t4 * 4 + 1) * 6], h1);
          h2 = fmaf(a.z + b.z, Wk[(t4 * 4 + 2) * 6], h2);
          h3 = fmaf(a.w + b.w, Wk[(t4 * 4 + 3) * 6], h3);
        }
        h0 = fmaf(sx[cLocal][0][76] + sx[cLocal][1][76], Wk[76 * 6], h0);
        h1 = fmaf(sx[cLocal][0][77] + sx[cLocal][1][77], Wk[77 * 6], h1);
        float h = (h0 + h2) + (h1 + h3);
        h = (h > 0.f) ? h : NEG * h;
        orow[3 + lane] = h;
      } else if (lane < 33) {
        orow[lane - 30] = (lane == 30) ? cx : ((lane == 31) ? cy : cz);
      }
    }
}

extern "C" void kernel_launch(void* const* d_in, const int* in_sizes, int n_in,
                              void* d_out, int out_size, void* d_ws, size_t ws_size,
                              hipStream_t stream) {
    const float* points = (const float*)d_in[0];  // 2*1024*6
    const float* W      = (const float*)d_in[1];  // 5*78*6
    const float* bias   = (const float*)d_in[2];  // 30
    float* out          = (float*)d_out;          // 2*1024*33
    // 1024 blocks x 8 waves = 2048 centers x 2 probe-halves x 2 nn-halves
    crossconv_kernel<<<1024, 512, 0, stream>>>(points, W, bias, out);
}

// Round 8
// 23.737 us; speedup vs baseline: 2.7409x; 1.1111x over previous
//
#include <hip/hip_runtime.h>

// CrossConvV2: B=2, n=1024, d=3, f=3, m=26 probes, k=5 convs, o=6 out_feats.
// out[b,l] = [coords(3) | leakyrelu( (wf flat 78 * 10/n) @ W[k] + b[k] ) (30)]
// wf[b,l,m,ff] = sum_nn 1/(|c_nn - c_l - p_m|^2 + 10) * feats[nn,ff]
// |c_nn - c_l - p|^2 + 10 = |d|^2 + 19 - 2 d.p   (|p| = 3 for all probes)
//
// R7: I$ theory. R0-R6 pinned at 24-26us with ~70% of issue slots empty at
// ANY occupancy -> suspect front-end: fully-unrolled 16-iter body is ~20-30KB,
// 32 waves/CU at different PCs need ~128B/cyc fetch. Fix: #pragma unroll 2
// on the neighbor loop (body ~1.2KB, I$-resident), everything else = R3
// (best at 23.9us, VGPR 52, no spill).

#define NPTS      1024
#define COEFF     10.0f
#define NEG       0.3f

constexpr float PROBE[26][3] = {
  {-2.12132034f,  1.95984445f, -0.81179415f},
  {-2.12132034f,  1.95984445f,  0.81179415f},
  {-2.12132034f,  0.81179415f,  1.95984445f},
  {-2.12132034f, -0.81179415f,  1.95984445f},
  {-2.12132034f, -1.95984445f,  0.81179415f},
  {-2.12132034f, -1.95984445f, -0.81179415f},
  {-2.12132034f, -0.81179415f, -1.95984445f},
  {-2.12132034f,  0.81179415f, -1.95984445f},
  { 0.0f,         3.0f,         0.0f       },
  { 0.0f,         2.12132034f,  2.12132034f},
  { 0.0f,         0.0f,         3.0f       },
  { 0.0f,        -2.12132034f,  2.12132034f},
  { 0.0f,        -3.0f,         0.0f       },
  { 0.0f,        -2.12132034f, -2.12132034f},
  { 0.0f,         0.0f,        -3.0f       },
  { 0.0f,         2.12132034f, -2.12132034f},
  { 2.12132034f,  1.95984445f,  0.81179415f},
  { 2.12132034f,  0.81179415f,  1.95984445f},
  { 2.12132034f, -0.81179415f,  1.95984445f},
  { 2.12132034f, -1.95984445f,  0.81179415f},
  { 2.12132034f, -1.95984445f, -0.81179415f},
  { 2.12132034f, -0.81179415f, -1.95984445f},
  { 2.12132034f,  0.81179415f, -1.95984445f},
  { 2.12132034f,  1.95984445f, -0.81179415f},
  {-3.0f,         0.0f,         0.0f       },
  { 3.0f,         0.0f,         0.0f       },
};

// half0: ring x=-2.121 (8) + y/z-axials (4) + x-axials (2) = 14 probes
// half1: ring x=+2.121 (8) + diagonal quads (4)            = 12 probes
constexpr int H0[14] = {0,1,2,3,4,5,6,7, 8,12,10,14, 24,25};
constexpr int H1[14] = {16,17,18,19,20,21,22,23, 9,11,13,15, 0,0}; // pad

// wave64 sum-reduce via DPP (result valid in lane 63). rocPRIM pattern.
#define DPP_STEP(x, ctrl, rm, bm, bc)                                        \
  x += __int_as_float(__builtin_amdgcn_update_dpp(                           \
      0, __float_as_int(x), ctrl, rm, bm, bc))

__device__ __forceinline__ float wave_sum_to_lane63(float x) {
  DPP_STEP(x, 0x111, 0xf, 0xf, true);   // row_shr:1
  DPP_STEP(x, 0x112, 0xf, 0xf, true);   // row_shr:2
  DPP_STEP(x, 0x114, 0xf, 0xe, false);  // row_shr:4
  DPP_STEP(x, 0x118, 0xf, 0xc, false);  // row_shr:8
  DPP_STEP(x, 0x142, 0xa, 0xf, false);  // row_bcast:15 -> rows 1,3
  DPP_STEP(x, 0x143, 0xc, 0xf, false);  // row_bcast:31 -> rows 2,3
  return x;                              // lane 63 = full sum
}

// t-generation with compile-time zero-skip; shared subtrees CSE via GVN
template <int HALF, int J>
struct TGen {
  static __device__ __forceinline__ void run(float base, float dx, float dy,
                                             float dz, float* t) {
    TGen<HALF, J - 1>::run(base, dx, dy, dz, t);
    constexpr int   m   = HALF ? H1[J] : H0[J];
    constexpr float px2 = -2.0f * PROBE[m][0];
    constexpr float py2 = -2.0f * PROBE[m][1];
    constexpr float pz2 = -2.0f * PROBE[m][2];
    float v = base;                         // x innermost: ring-shared CSE
    if constexpr (px2 != 0.0f) v = fmaf(px2, dx, v);
    if constexpr (py2 != 0.0f) v = fmaf(py2, dy, v);
    if constexpr (pz2 != 0.0f) v = fmaf(pz2, dz, v);
    t[J] = v;
  }
};
template <int HALF>
struct TGen<HALF, -1> {
  static __device__ __forceinline__ void run(float, float, float, float, float*) {}
};

// batched reciprocal: 1 rcp + 9 mul for 4 values (vs 4 rcp)
__device__ __forceinline__ void rcp4(const float* t, float* w) {
  const float p01 = t[0] * t[1], p23 = t[2] * t[3];
  const float r   = __builtin_amdgcn_rcpf(p01 * p23);
  const float r01 = p23 * r, r23 = p01 * r;
  w[0] = t[1] * r01;  w[1] = t[0] * r01;
  w[2] = t[3] * r23;  w[3] = t[2] * r23;
}
__device__ __forceinline__ void rcp2(const float* t, float* w) {
  const float r = __builtin_amdgcn_rcpf(t[0] * t[1]);
  w[0] = t[1] * r;  w[1] = t[0] * r;
}

template <int HALF>
__device__ void run_main(const float* __restrict__ batch,
                         int lane, float cx, float cy, float cz, float* acc) {
  constexpr int NP = HALF ? 12 : 14;
  #pragma unroll 2
  for (int it = 0; it < NPTS / 64; ++it) {
    const float* prow = batch + (it * 64 + lane) * 6;
    const float2 q0 = *reinterpret_cast<const float2*>(prow);
    const float2 q1 = *reinterpret_cast<const float2*>(prow + 2);
    const float2 q2 = *reinterpret_cast<const float2*>(prow + 4);
    const float dx = q0.x - cx, dy = q0.y - cy, dz = q1.x - cz;
    const float f0 = q1.y, f1 = q2.x, f2 = q2.y;
    const float base = fmaf(dx, dx, fmaf(dy, dy, fmaf(dz, dz, 19.0f)));

    float t[NP], w[NP];
    TGen<HALF, NP - 1>::run(base, dx, dy, dz, t);
    rcp4(t + 0, w + 0);
    rcp4(t + 4, w + 4);
    rcp4(t + 8, w + 8);
    if constexpr (NP == 14) rcp2(t + 12, w + 12);

    #pragma unroll
    for (int j = 0; j < NP; ++j) {
      acc[j * 3 + 0] = fmaf(w[j], f0, acc[j * 3 + 0]);
      acc[j * 3 + 1] = fmaf(w[j], f1, acc[j * 3 + 1]);
      acc[j * 3 + 2] = fmaf(w[j], f2, acc[j * 3 + 2]);
    }
  }
}

template <int HALF>
__device__ __forceinline__ void reduce_store(float* acc, int lane, int cLocal,
                                             float sx[2][80], float scale) {
  constexpr int NP = HALF ? 12 : 14;
  #pragma unroll
  for (int j = 0; j < NP * 3; ++j)
    acc[j] = wave_sum_to_lane63(acc[j]) * scale;
  if (lane == 63) {
    #pragma unroll
    for (int j = 0; j < NP; ++j) {
      const int m = HALF ? H1[j] : H0[j];
      sx[cLocal][m * 3 + 0] = acc[j * 3 + 0];
      sx[cLocal][m * 3 + 1] = acc[j * 3 + 1];
      sx[cLocal][m * 3 + 2] = acc[j * 3 + 2];
    }
  }
}

__global__ __launch_bounds__(256, 4) void crossconv_kernel(
    const float* __restrict__ points,  // (2,1024,6)
    const float* __restrict__ W,       // (5,78,6)
    const float* __restrict__ bias,    // (5,6) flat 30
    float* __restrict__ out)           // (2,1024,33)
{
    __shared__ __align__(16) float sx[2][80];

    const int tid    = threadIdx.x;
    const int lane   = tid & 63;
    const int w      = tid >> 6;          // wave in block: 0..3
    const int cLocal = w >> 1;            // center within block: 0,1
    const int half   = w & 1;             // probe half: 0,1
    const int G      = blockIdx.x * 2 + cLocal;   // global center 0..2047

    const float* batch = points + (G >> 10) * (NPTS * 6);
    const float* crow  = points + G * 6;
    const float  cx = crow[0], cy = crow[1], cz = crow[2];

    float acc[42];
    #pragma unroll
    for (int j = 0; j < 42; ++j) acc[j] = 0.f;

    if (half == 0) run_main<0>(batch, lane, cx, cy, cz, acc);
    else           run_main<1>(batch, lane, cx, cy, cz, acc);

    const float scale = COEFF / (float)NPTS;
    if (half == 0) reduce_store<0>(acc, lane, cLocal, sx, scale);
    else           reduce_store<1>(acc, lane, cLocal, sx, scale);
    __syncthreads();

    // tail: waves with half==0 do the 78->30 matmul + coords for their center
    if (half == 0) {
      float* orow = out + G * 33;
      if (lane < 30) {
        const int k = lane / 6, o = lane % 6;
        const float* Wk = W + k * (78 * 6) + o;  // W[k, t, o], stride 6 over t
        float h0 = bias[lane], h1 = 0.f, h2 = 0.f, h3 = 0.f;
        const float4* sxv = reinterpret_cast<const float4*>(sx[cLocal]);
        #pragma unroll
        for (int t4 = 0; t4 < 19; ++t4) {
          const float4 v = sxv[t4];
          h0 = fmaf(v.x, Wk[(t4 * 4 + 0) * 6], h0);
          h1 = fmaf(v.y, Wk[(t4 * 4 + 1) * 6], h1);
          h2 = fmaf(v.z, Wk[(t4 * 4 + 2) * 6], h2);
          h3 = fmaf(v.w, Wk[(t4 * 4 + 3) * 6], h3);
        }
        const float2 vt = *reinterpret_cast<const float2*>(&sx[cLocal][76]);
        h0 = fmaf(vt.x, Wk[76 * 6], h0);
        h1 = fmaf(vt.y, Wk[77 * 6], h1);
        float h = (h0 + h2) + (h1 + h3);
        h = (h > 0.f) ? h : NEG * h;
        orow[3 + lane] = h;
      } else if (lane < 33) {
        orow[lane - 30] = (lane == 30) ? cx : ((lane == 31) ? cy : cz);
      }
    }
}

extern "C" void kernel_launch(void* const* d_in, const int* in_sizes, int n_in,
                              void* d_out, int out_size, void* d_ws, size_t ws_size,
                              hipStream_t stream) {
    const float* points = (const float*)d_in[0];  // 2*1024*6
    const float* W      = (const float*)d_in[1];  // 5*78*6
    const float* bias   = (const float*)d_in[2];  // 30
    float* out          = (float*)d_out;          // 2*1024*33
    // 1024 blocks x 4 waves = 2048 centers x 2 probe-halves
    crossconv_kernel<<<1024, 256, 0, stream>>>(points, W, bias, out);
}